// Round 3
// baseline (435.907 us; speedup 1.0000x reference)
//
#include <hip/hip_runtime.h>

typedef _Float16 f16;
typedef _Float16 f16x4 __attribute__((ext_vector_type(4)));
typedef _Float16 f16x8 __attribute__((ext_vector_type(8)));
typedef float f32x4 __attribute__((ext_vector_type(4)));

#define CIN 28
#define TT 8
#define HW 16384

// gate pre-scales folded into weights: i,f,o rows scaled by -log2e so
// E=exp2(acc)=e^{-x} and sig(x)=1/(1+E); g rows scaled by +2log2e so
// E=exp2(acc)=e^{2x} and tanh(x)=(E-1)/(E+1).
#define S_SIG  (-1.44269504088896341f)
#define S_TANH ( 2.88539008177792681f)

// workspace layout (bytes)
#define WS_WX    0        // f16 [256][32]  folded Wih1*W_red (+denorm scales, gate scale)
#define WS_WHH1  16384    // f16 [256][64]
#define WS_W21   49152    // f16 [256][64]  folded Wih2*Wc1
#define WS_WHH2  81920    // f16 [256][64]
#define WS_BX    114688   // f32 [256]
#define WS_B2    115712   // f32 [256]
#define WS_WH    116736   // f32 [64]       folded W_head*Wc2
#define WS_BH    116992   // f32 [1]

// Fused LSTM cell activation: 5 exp2 + 2 rcp (sig(f) shares the i/g rcp:
// r3 = 1/((1+Ei)(1+Eg)(1+Ef)); cn = r3*(pig*c + (Eg-1)*pf) = c/pf + (Eg-1)/pig).
// Gate magnitudes here are <~0.5 (0.05-scale weights), so pig*pf is O(10):
// no overflow risk, rounding at f32-ulp level.
__device__ __forceinline__ float lstm_act(float gi, float gf, float gg, float go,
                                          float& c) {
  const float Ei = __builtin_amdgcn_exp2f(gi);
  const float Ef = __builtin_amdgcn_exp2f(gf);
  const float Eg = __builtin_amdgcn_exp2f(gg);
  const float Eo = __builtin_amdgcn_exp2f(go);
  const float pig = (1.f + Ei) * (1.f + Eg);
  const float pf  = 1.f + Ef;
  const float r3  = __builtin_amdgcn_rcpf(pig * pf);
  const float t1  = (Eg - 1.f) * pf;
  const float cn  = r3 * __builtin_fmaf(pig, c, t1);
  c = cn;
  const float Ec  = __builtin_amdgcn_exp2f(cn * S_TANH);
  const float roc = __builtin_amdgcn_rcpf((1.f + Eo) * (1.f + Ec));
  return (Ec - 1.f) * roc;
}

// Parallel prep: 256 blocks (one per gate row g) x 64 threads (one per k).
__global__ __launch_bounds__(64) void prep_kernel(
    const float* __restrict__ W_red, const float* __restrict__ b_red,
    const float* __restrict__ Wih1, const float* __restrict__ Whh1,
    const float* __restrict__ bih1, const float* __restrict__ bhh1,
    const float* __restrict__ Wc1,  const float* __restrict__ bc1,
    const float* __restrict__ Wih2, const float* __restrict__ Whh2,
    const float* __restrict__ bih2, const float* __restrict__ bhh2,
    const float* __restrict__ Wc2,  const float* __restrict__ bc2,
    const float* __restrict__ W_head, const float* __restrict__ b_head,
    unsigned char* __restrict__ ws)
{
  const int g = blockIdx.x;    // 0..255 gate row
  const int k = threadIdx.x;   // 0..63
  f16* WxH   = (f16*)(ws + WS_WX);
  f16* Whh1H = (f16*)(ws + WS_WHH1);
  f16* W21H  = (f16*)(ws + WS_W21);
  f16* Whh2H = (f16*)(ws + WS_WHH2);
  float* BX  = (float*)(ws + WS_BX);
  float* B2  = (float*)(ws + WS_B2);
  float* WHp = (float*)(ws + WS_WH);
  float* BHp = (float*)(ws + WS_BH);

  const float sc = ((g >> 6) == 2) ? S_TANH : S_SIG;  // gate g uses tanh

  // Wx[g][k] = Wih1[g,:] @ W_red[:,k]  (k < CIN), + u/v denorm fold
  float wxv = 0.f;
  if (k < CIN) {
    float s = 0.f;
    for (int r = 0; r < 24; ++r) s += Wih1[g*24 + r] * W_red[r*28 + k];
    wxv = s;
  }
  const float wx11 = __shfl(wxv, 11, 64);   // pre-scale values for bias fold
  const float wx12 = __shfl(wxv, 12, 64);
  if (k == 11) wxv *= 0.15f;                // SD_U
  if (k == 12) wxv *= 0.12f;                // SD_V
  if (k < 32) WxH[g*32 + k] = (f16)(wxv * sc);

  Whh1H[g*64 + k] = (f16)(Whh1[g*64 + k] * sc);
  Whh2H[g*64 + k] = (f16)(Whh2[g*64 + k] * sc);

  // W21[g][k] = Wih2[g,:] @ Wc1[:,k]   (Wih2 row broadcast, Wc1 coalesced)
  {
    float s = 0.f;
    for (int m = 0; m < 64; ++m) s += Wih2[g*64 + m] * Wc1[m*64 + k];
    W21H[g*64 + k] = (f16)(s * sc);
  }

  if (k == 0) {
    float bx = bih1[g] + bhh1[g];
    for (int r = 0; r < 24; ++r) bx += Wih1[g*24 + r] * b_red[r];
    bx += wx11 * 0.02f + wx12 * (-0.01f);   // MU_U, MU_V
    BX[g] = bx * sc;
    float b2v = bih2[g] + bhh2[g];
    for (int m = 0; m < 64; ++m) b2v += Wih2[g*64 + m] * bc1[m];
    B2[g] = b2v * sc;
  }
  if (g == 0) {
    float s = 0.f;
    for (int m = 0; m < 64; ++m) s += W_head[m] * Wc2[m*64 + k];
    WHp[k] = s;
    if (k == 0) {
      float s2 = b_head[0];
      for (int m = 0; m < 64; ++m) s2 += W_head[m] * bc2[m];
      BHp[0] = s2;
    }
  }
}

// 64 pixels/block, 4 waves; wave w owns hidden cols [16w,16w+16) x all 4
// gates for all 64 pixels.
//
// Swapped-operand MFMA: A = weights ([gate_row][k], lane m=cl holds row,
// k=8*qd+j), B = activations ([pixel][k], lane n=cl holds pixel's k-slice).
// D[row=gate_row][col=pixel]: thread (cl,qd) holds gate rows 4qd+r of pixel
// cl -> its 4 h outputs are CONTIGUOUS hidden cols of one pixel (one
// ds_write_b64 instead of 4 scalar b16 writes), and the bias is a contiguous
// f32x4 (loaded once, used as the MFMA C operand: no per-chain splats).
//
// ALL MFMAs are __builtins: the compiler sees every VALU<->MFMA interface
// (bias C in, acc out to lstm_act) and handles hazards itself. gfx950's
// unified VGPR/AGPR file + AV register classes let the RA home cold weight
// fragments in AGPRs on its own — no inline-asm pinning needed. c2 state is
// a plain float (RA-managed), dropping the accvgpr read/write round-trips.
__global__ __launch_bounds__(256)
__attribute__((amdgpu_waves_per_eu(2, 2)))
void convlstm_main(
    const float* __restrict__ x, const unsigned char* __restrict__ ws,
    float* __restrict__ out)
{
  __shared__ __align__(16) f16 xs[2][64 * 40];       // [pixel][ch], stride 40
  __shared__ __align__(16) f16 h1buf[2][64 * 72];    // [pixel][hid], stride 72
  __shared__ __align__(16) f16 h2buf[2][64 * 72];

  const int tid  = threadIdx.x;
  const int lane = tid & 63;
  const int wv   = tid >> 6;     // wave 0..3
  const int cl   = lane & 15;    // MFMA "lane&15"
  const int qd   = lane >> 4;    // MFMA quad

  const f16* WxG   = (const f16*)(ws + WS_WX);
  const f16* Whh1G = (const f16*)(ws + WS_WHH1);
  const f16* W21G  = (const f16*)(ws + WS_W21);
  const f16* Whh2G = (const f16*)(ws + WS_WHH2);
  const float* BX  = (const float*)(ws + WS_BX);
  const float* B2  = (const float*)(ws + WS_B2);

  // ---- weight fragments (A layout: [m=gate-row][k]) ----
  f16x8 wx[4];                       // k 0..31 (x channels + zero pad)
  f16x8 whh1k0[4], whh1k1[4];        // k 0..31 / 32..63
  f16x8 w21k0[4],  w21k1[4];
  f16x8 whh2k0[4], whh2k1[4];
  f32x4 bxq[4], b2q[4];              // per-thread bias rows (gate rows 4qd..)
#pragma unroll
  for (int P = 0; P < 4; ++P) {                      // i,f,g,o
    const int gr = 64*P + 16*wv + cl;
    wx[P]     = *(const f16x8*)(WxG + gr*32 + qd*8);
    whh1k0[P] = *(const f16x8*)(Whh1G + gr*64 + qd*8);
    whh1k1[P] = *(const f16x8*)(Whh1G + gr*64 + 32 + qd*8);
    w21k0[P]  = *(const f16x8*)(W21G  + gr*64 + qd*8);
    w21k1[P]  = *(const f16x8*)(W21G  + gr*64 + 32 + qd*8);
    whh2k0[P] = *(const f16x8*)(Whh2G + gr*64 + qd*8);
    whh2k1[P] = *(const f16x8*)(Whh2G + gr*64 + 32 + qd*8);
    bxq[P] = *(const f32x4*)(BX + 64*P + 16*wv + 4*qd);
    b2q[P] = *(const f32x4*)(B2 + 64*P + 16*wv + 4*qd);
  }

  // zero t=0 h buffers
  {
    unsigned* z1 = (unsigned*)&h1buf[0][0];
    unsigned* z2 = (unsigned*)&h2buf[0][0];
#pragma unroll
    for (int i = tid; i < 2304; i += 256) { z1[i] = 0u; z2[i] = 0u; }
  }

  const int gpix = blockIdx.x * 64;
  const float* xb = x + (size_t)(gpix >> 14) * (TT * CIN * HW) + (gpix & (HW - 1));

  const int sp = lane;        // staging pixel
  const int cb = wv * 8;      // staging channel base: 0,8,16,24

  // stage x_0: one f16x8 (ds_write_b128) per thread
  {
    f16x8 v;
#pragma unroll
    for (int j = 0; j < 8; ++j) {
      const int ch = cb + j;
      v[j] = (ch < CIN) ? (f16)xb[ch*HW + sp] : (f16)0.f;
    }
    *(f16x8*)(&xs[0][sp*40 + cb]) = v;
  }
  __syncthreads();

  float c1s[4][4];
  float c2s[4][4];
#pragma unroll
  for (int a = 0; a < 4; ++a)
#pragma unroll
    for (int b = 0; b < 4; ++b) { c1s[a][b] = 0.f; c2s[a][b] = 0.f; }

#pragma unroll 1
  for (int t = 0; t < TT; ++t) {
    // ---- prefetch x_{t+1}, converting to f16 at load (4 regs not 8) ----
    f16x8 xrv;
    if (t + 1 < TT) {
      const float* xt = xb + (size_t)(t + 1) * (CIN * HW);
#pragma unroll
      for (int j = 0; j < 8; ++j) {
        const int ch = cb + j;
        xrv[j] = (ch < CIN) ? (f16)xt[ch*HW + sp] : (f16)0.f;
      }
    }

    const f16* xsr = xs[t & 1];
    const f16* h1r = h1buf[t & 1];
    const f16* h2r = h2buf[t & 1];
    f16* h1w = h1buf[(t + 1) & 1];
    f16* h2w = h2buf[(t + 1) & 1];

    // ---- layer 1: gates = Whh1*h1 + Wx*x + bx (bias as C operand) ----
#pragma unroll
    for (int mb = 0; mb < 4; ++mb) {
      const int p = 16*mb + cl;
      const f16x8 ax  = *(const f16x8*)(xsr + p*40 + qd*8);
      const f16x8 ah0 = *(const f16x8*)(h1r + p*72 + qd*8);
      const f16x8 ah1 = *(const f16x8*)(h1r + p*72 + 32 + qd*8);
      f32x4 acc[4];
#pragma unroll
      for (int P = 0; P < 4; ++P) {
        acc[P] = __builtin_amdgcn_mfma_f32_16x16x32_f16(whh1k0[P], ah0, bxq[P], 0, 0, 0);
        acc[P] = __builtin_amdgcn_mfma_f32_16x16x32_f16(whh1k1[P], ah1, acc[P], 0, 0, 0);
        acc[P] = __builtin_amdgcn_mfma_f32_16x16x32_f16(wx[P],     ax,  acc[P], 0, 0, 0);
      }
      float hn[4];
#pragma unroll
      for (int r = 0; r < 4; ++r)
        hn[r] = lstm_act(acc[0][r], acc[1][r], acc[2][r], acc[3][r], c1s[mb][r]);
      f16x4 hv; hv[0] = (f16)hn[0]; hv[1] = (f16)hn[1];
      hv[2] = (f16)hn[2]; hv[3] = (f16)hn[3];
      *(f16x4*)(h1w + p*72 + 16*wv + 4*qd) = hv;   // one ds_write_b64
    }
    __syncthreads();

    // ---- store prefetched x_{t+1}: overlaps layer-2 MFMA (LDS-write pipe) ----
    if (t + 1 < TT) {
      f16* xsw = xs[(t + 1) & 1];
      *(f16x8*)(xsw + sp*40 + cb) = xrv;
    }

    // ---- layer 2: gates = W21*h1_new + Whh2*h2 + b2 (bias as C operand) ----
#pragma unroll
    for (int mb = 0; mb < 4; ++mb) {
      const int p = 16*mb + cl;
      const f16x8 an0 = *(const f16x8*)(h1w + p*72 + qd*8);
      const f16x8 an1 = *(const f16x8*)(h1w + p*72 + 32 + qd*8);
      const f16x8 a20 = *(const f16x8*)(h2r + p*72 + qd*8);
      const f16x8 a21 = *(const f16x8*)(h2r + p*72 + 32 + qd*8);
      f32x4 acc[4];
#pragma unroll
      for (int P = 0; P < 4; ++P) {
        acc[P] = __builtin_amdgcn_mfma_f32_16x16x32_f16(w21k0[P],  an0, b2q[P], 0, 0, 0);
        acc[P] = __builtin_amdgcn_mfma_f32_16x16x32_f16(w21k1[P],  an1, acc[P], 0, 0, 0);
        acc[P] = __builtin_amdgcn_mfma_f32_16x16x32_f16(whh2k0[P], a20, acc[P], 0, 0, 0);
        acc[P] = __builtin_amdgcn_mfma_f32_16x16x32_f16(whh2k1[P], a21, acc[P], 0, 0, 0);
      }
      float hn[4];
#pragma unroll
      for (int r = 0; r < 4; ++r)
        hn[r] = lstm_act(acc[0][r], acc[1][r], acc[2][r], acc[3][r], c2s[mb][r]);
      f16x4 hv; hv[0] = (f16)hn[0]; hv[1] = (f16)hn[1];
      hv[2] = (f16)hn[2]; hv[3] = (f16)hn[3];
      *(f16x4*)(h2w + p*72 + 16*wv + 4*qd) = hv;
    }
    __syncthreads();
  }

  // ---- head epilogue: out[p] = bhead + sum_k h2[p][k] * wh[k] ----
  if (tid < 64) {
    const float* wh = (const float*)(ws + WS_WH);
    const f16* row = &h2buf[0][tid * 72];   // final h2 lives in buffer 0
    float s = *((const float*)(ws + WS_BH));
#pragma unroll
    for (int k = 0; k < 64; ++k) s += (float)row[k] * wh[k];
    out[gpix + tid] = s;
  }
}

extern "C" void kernel_launch(void* const* d_in, const int* in_sizes, int n_in,
                              void* d_out, int out_size, void* d_ws, size_t ws_size,
                              hipStream_t stream) {
  const float* x      = (const float*)d_in[0];
  const float* W_red  = (const float*)d_in[1];
  const float* b_red  = (const float*)d_in[2];
  const float* Wih1   = (const float*)d_in[3];
  const float* Whh1   = (const float*)d_in[4];
  const float* bih1   = (const float*)d_in[5];
  const float* bhh1   = (const float*)d_in[6];
  const float* Wc1    = (const float*)d_in[7];
  const float* bc1    = (const float*)d_in[8];
  const float* Wih2   = (const float*)d_in[9];
  const float* Whh2   = (const float*)d_in[10];
  const float* bih2   = (const float*)d_in[11];
  const float* bhh2   = (const float*)d_in[12];
  const float* Wc2    = (const float*)d_in[13];
  const float* bc2    = (const float*)d_in[14];
  const float* W_head = (const float*)d_in[15];
  const float* b_head = (const float*)d_in[16];

  prep_kernel<<<256, 64, 0, stream>>>(W_red, b_red, Wih1, Whh1, bih1, bhh1,
                                      Wc1, bc1, Wih2, Whh2, bih2, bhh2,
                                      Wc2, bc2, W_head, b_head,
                                      (unsigned char*)d_ws);
  convlstm_main<<<2048, 256, 0, stream>>>(x, (const unsigned char*)d_ws,
                                          (float*)d_out);
}

// Round 4
// 386.156 us; speedup vs baseline: 1.1288x; 1.1288x over previous
//
#include <hip/hip_runtime.h>

typedef _Float16 f16;
typedef _Float16 f16x2 __attribute__((ext_vector_type(2)));
typedef _Float16 f16x4 __attribute__((ext_vector_type(4)));
typedef _Float16 f16x8 __attribute__((ext_vector_type(8)));
typedef float f32x4 __attribute__((ext_vector_type(4)));

#define CIN 28
#define TT 8
#define HW 16384

// gate pre-scales folded into weights: i,f,o rows scaled by -log2e so
// E=exp2(acc)=e^{-x} and sig(x)=1/(1+E); g rows scaled by +2log2e so
// E=exp2(acc)=e^{2x} and tanh(x)=(E-1)/(E+1).
#define S_SIG  (-1.44269504088896341f)
#define S_TANH ( 2.88539008177792681f)

// workspace layout (bytes). Weight matrices stored in PACKED gate-row order:
//   pr = wave*32 + rt*16 + colpos*4 + gate,  col = 8*wave + 2*colpos + rt
// so a wave's 32 rows are 2 contiguous 16-row MFMA tiles, and within a tile
// thread quad qd holds rows 4qd..4qd+3 = all 4 gates of ONE hidden col.
#define WS_WX    0        // f16 [256][32]  folded Wih1*W_red (+denorm, gate scale)
#define WS_WHH1  16384    // f16 [256][64]
#define WS_W21   49152    // f16 [256][64]  folded Wih2*Wc1
#define WS_WHH2  81920    // f16 [256][64]
#define WS_BX    114688   // f32 [256]  packed order
#define WS_B2    115712   // f32 [256]  packed order
#define WS_WH    116736   // f32 [64]   folded W_head*Wc2 (ORIGINAL col order)
#define WS_BH    116992   // f32 [1]

// Fused LSTM cell activation: 5 exp2 + 2 rcp (sig(f) shares the i/g rcp:
// r3 = 1/((1+Ei)(1+Eg)(1+Ef)); cn = r3*(pig*c + (Eg-1)*pf) = c/pf + (Eg-1)/pig).
__device__ __forceinline__ float lstm_act(float gi, float gf, float gg, float go,
                                          float& c) {
  const float Ei = __builtin_amdgcn_exp2f(gi);
  const float Ef = __builtin_amdgcn_exp2f(gf);
  const float Eg = __builtin_amdgcn_exp2f(gg);
  const float Eo = __builtin_amdgcn_exp2f(go);
  const float pig = (1.f + Ei) * (1.f + Eg);
  const float pf  = 1.f + Ef;
  const float r3  = __builtin_amdgcn_rcpf(pig * pf);
  const float t1  = (Eg - 1.f) * pf;
  const float cn  = r3 * __builtin_fmaf(pig, c, t1);
  c = cn;
  const float Ec  = __builtin_amdgcn_exp2f(cn * S_TANH);
  const float roc = __builtin_amdgcn_rcpf((1.f + Eo) * (1.f + Ec));
  return (Ec - 1.f) * roc;
}

// Parallel prep: 256 blocks (one per ORIGINAL gate row g) x 64 threads (k).
__global__ __launch_bounds__(64) void prep_kernel(
    const float* __restrict__ W_red, const float* __restrict__ b_red,
    const float* __restrict__ Wih1, const float* __restrict__ Whh1,
    const float* __restrict__ bih1, const float* __restrict__ bhh1,
    const float* __restrict__ Wc1,  const float* __restrict__ bc1,
    const float* __restrict__ Wih2, const float* __restrict__ Whh2,
    const float* __restrict__ bih2, const float* __restrict__ bhh2,
    const float* __restrict__ Wc2,  const float* __restrict__ bc2,
    const float* __restrict__ W_head, const float* __restrict__ b_head,
    unsigned char* __restrict__ ws)
{
  const int g = blockIdx.x;    // 0..255 ORIGINAL gate row: gate = g>>6, col = g&63
  const int k = threadIdx.x;   // 0..63
  f16* WxH   = (f16*)(ws + WS_WX);
  f16* Whh1H = (f16*)(ws + WS_WHH1);
  f16* W21H  = (f16*)(ws + WS_W21);
  f16* Whh2H = (f16*)(ws + WS_WHH2);
  float* BX  = (float*)(ws + WS_BX);
  float* B2  = (float*)(ws + WS_B2);
  float* WHp = (float*)(ws + WS_WH);
  float* BHp = (float*)(ws + WS_BH);

  const int gate = g >> 6;
  const int col  = g & 63;
  // packed destination row: col = 8*wv + 2*cpos + rt
  const int pr = (col >> 3) * 32 + (col & 1) * 16 + ((col >> 1) & 3) * 4 + gate;

  const float sc = (gate == 2) ? S_TANH : S_SIG;  // gate g uses tanh

  // Wx[g][k] = Wih1[g,:] @ W_red[:,k]  (k < CIN), + u/v denorm fold
  float wxv = 0.f;
  if (k < CIN) {
    float s = 0.f;
    for (int r = 0; r < 24; ++r) s += Wih1[g*24 + r] * W_red[r*28 + k];
    wxv = s;
  }
  const float wx11 = __shfl(wxv, 11, 64);   // pre-scale values for bias fold
  const float wx12 = __shfl(wxv, 12, 64);
  if (k == 11) wxv *= 0.15f;                // SD_U
  if (k == 12) wxv *= 0.12f;                // SD_V
  if (k < 32) WxH[pr*32 + k] = (f16)(wxv * sc);

  Whh1H[pr*64 + k] = (f16)(Whh1[g*64 + k] * sc);
  Whh2H[pr*64 + k] = (f16)(Whh2[g*64 + k] * sc);

  // W21[g][k] = Wih2[g,:] @ Wc1[:,k]   (k = ORIGINAL h1 col, unpermuted)
  {
    float s = 0.f;
    for (int m = 0; m < 64; ++m) s += Wih2[g*64 + m] * Wc1[m*64 + k];
    W21H[pr*64 + k] = (f16)(s * sc);
  }

  if (k == 0) {
    float bx = bih1[g] + bhh1[g];
    for (int r = 0; r < 24; ++r) bx += Wih1[g*24 + r] * b_red[r];
    bx += wx11 * 0.02f + wx12 * (-0.01f);   // MU_U, MU_V
    BX[pr] = bx * sc;
    float b2v = bih2[g] + bhh2[g];
    for (int m = 0; m < 64; ++m) b2v += Wih2[g*64 + m] * bc1[m];
    B2[pr] = b2v * sc;
  }
  if (g == 0) {
    float s = 0.f;
    for (int m = 0; m < 64; ++m) s += W_head[m] * Wc2[m*64 + k];
    WHp[k] = s;
    if (k == 0) {
      float s2 = b_head[0];
      for (int m = 0; m < 64; ++m) s2 += W_head[m] * bc2[m];
      BHp[0] = s2;
    }
  }
}

// 64 pixels/block, 8 waves (512 threads); wave w owns hidden cols 8w..8w+7
// (x all 4 gates) as 2 packed row-tiles. Per-wave weight residency is halved
// vs the 4-wave version (56 VGPRs), and __launch_bounds__(512,4) forces the
// <=128-reg allocation needed for 2 blocks/CU = 4 waves/SIMD (2x occupancy;
// round-3 counters showed the kernel latency-bound at 58% combined issue).
//
// Swapped-operand MFMA: A = weights (packed rows), B = activations. Per
// D-tile, thread (cl,qd) holds rows 4qd+r = the 4 GATES of hidden col
// (8wv+2qd+rt), pixel cl -> one lstm_act per tile, and the rt=0/1 results
// are ADJACENT cols -> one packed ds_write_b32 ((4cl+qd)%32 banks: 2-way,
// free). Bias is a contiguous f32x4 in packed order, used as MFMA C operand.
// All MFMAs are __builtins (compiler owns every hazard).
__global__ __launch_bounds__(512, 4)
void convlstm_main(
    const float* __restrict__ x, const unsigned char* __restrict__ ws,
    float* __restrict__ out)
{
  __shared__ __align__(16) f16 xs[2][64 * 40];       // [pixel][ch], stride 40
  __shared__ __align__(16) f16 h1buf[2][64 * 72];    // [pixel][hid], stride 72
  __shared__ __align__(16) f16 h2buf[2][64 * 72];

  const int tid  = threadIdx.x;
  const int lane = tid & 63;
  const int wv   = tid >> 6;     // wave 0..7
  const int cl   = lane & 15;    // MFMA "lane&15" (pixel within tile / A row)
  const int qd   = lane >> 4;    // MFMA quad

  const f16* WxG   = (const f16*)(ws + WS_WX);
  const f16* Whh1G = (const f16*)(ws + WS_WHH1);
  const f16* W21G  = (const f16*)(ws + WS_W21);
  const f16* Whh2G = (const f16*)(ws + WS_WHH2);
  const float* BX  = (const float*)(ws + WS_BX);
  const float* B2  = (const float*)(ws + WS_B2);

  // ---- weight fragments (A layout: m=cl -> packed row, k=8qd+j) ----
  f16x8 wx[2];                      // k 0..31
  f16x8 whh1[2][2], w21[2][2], whh2[2][2];   // [rt][k-half]
  f32x4 bxq[2], b2q[2];             // rows 4qd..4qd+3 of each row-tile
#pragma unroll
  for (int rt = 0; rt < 2; ++rt) {
    const int pr = wv*32 + rt*16 + cl;
    wx[rt]      = *(const f16x8*)(WxG + pr*32 + qd*8);
    whh1[rt][0] = *(const f16x8*)(Whh1G + pr*64 + qd*8);
    whh1[rt][1] = *(const f16x8*)(Whh1G + pr*64 + 32 + qd*8);
    w21[rt][0]  = *(const f16x8*)(W21G  + pr*64 + qd*8);
    w21[rt][1]  = *(const f16x8*)(W21G  + pr*64 + 32 + qd*8);
    whh2[rt][0] = *(const f16x8*)(Whh2G + pr*64 + qd*8);
    whh2[rt][1] = *(const f16x8*)(Whh2G + pr*64 + 32 + qd*8);
    bxq[rt] = *(const f32x4*)(BX + wv*32 + rt*16 + 4*qd);
    b2q[rt] = *(const f32x4*)(B2 + wv*32 + rt*16 + 4*qd);
  }

  // zero t=0 h buffers (buffer 0 of each)
  {
    unsigned* z1 = (unsigned*)&h1buf[0][0];
    unsigned* z2 = (unsigned*)&h2buf[0][0];
#pragma unroll
    for (int i = tid; i < 2304; i += 512) { z1[i] = 0u; z2[i] = 0u; }
  }

  const int gpix = blockIdx.x * 64;
  const float* xb = x + (size_t)(gpix >> 14) * (TT * CIN * HW) + (gpix & (HW - 1));

  const int sp = lane;        // staging pixel (coalesced per wave)
  const int cg = wv;          // channel group: ch = 4cg..4cg+3

  // stage x_0: one f16x4 (ds_write_b64) per thread
  {
    f16x4 v;
#pragma unroll
    for (int j = 0; j < 4; ++j) {
      const int ch = cg*4 + j;
      v[j] = (ch < CIN) ? (f16)xb[ch*HW + sp] : (f16)0.f;
    }
    *(f16x4*)(&xs[0][sp*40 + cg*4]) = v;
  }
  __syncthreads();

  float c1s[4][2];   // [mb][rt]
  float c2s[4][2];
#pragma unroll
  for (int a = 0; a < 4; ++a)
#pragma unroll
    for (int b = 0; b < 2; ++b) { c1s[a][b] = 0.f; c2s[a][b] = 0.f; }

#pragma unroll 1
  for (int t = 0; t < TT; ++t) {
    // ---- prefetch x_{t+1}, f16 at load (2 regs) ----
    f16x4 xrv;
    if (t + 1 < TT) {
      const float* xt = xb + (size_t)(t + 1) * (CIN * HW);
#pragma unroll
      for (int j = 0; j < 4; ++j) {
        const int ch = cg*4 + j;
        xrv[j] = (ch < CIN) ? (f16)xt[ch*HW + sp] : (f16)0.f;
      }
    }

    const f16* xsr = xs[t & 1];
    const f16* h1r = h1buf[t & 1];
    const f16* h2r = h2buf[t & 1];
    f16* h1w = h1buf[(t + 1) & 1];
    f16* h2w = h2buf[(t + 1) & 1];

    // ---- layer 1: gates = Whh1*h1 + Wx*x + bx (bias as C operand) ----
#pragma unroll
    for (int mb = 0; mb < 4; ++mb) {
      const int p = 16*mb + cl;
      const f16x8 ax  = *(const f16x8*)(xsr + p*40 + qd*8);
      const f16x8 ah0 = *(const f16x8*)(h1r + p*72 + qd*8);
      const f16x8 ah1 = *(const f16x8*)(h1r + p*72 + 32 + qd*8);
      float hn[2];
#pragma unroll
      for (int rt = 0; rt < 2; ++rt) {
        f32x4 acc;
        acc = __builtin_amdgcn_mfma_f32_16x16x32_f16(whh1[rt][0], ah0, bxq[rt], 0, 0, 0);
        acc = __builtin_amdgcn_mfma_f32_16x16x32_f16(whh1[rt][1], ah1, acc, 0, 0, 0);
        acc = __builtin_amdgcn_mfma_f32_16x16x32_f16(wx[rt],      ax,  acc, 0, 0, 0);
        hn[rt] = lstm_act(acc[0], acc[1], acc[2], acc[3], c1s[mb][rt]);
      }
      f16x2 hv; hv[0] = (f16)hn[0]; hv[1] = (f16)hn[1];
      *(f16x2*)(h1w + p*72 + 8*wv + 2*qd) = hv;    // one ds_write_b32
    }
    __syncthreads();

    // ---- store prefetched x_{t+1}: overlaps layer-2 MFMA ----
    if (t + 1 < TT) {
      f16* xsw = xs[(t + 1) & 1];
      *(f16x4*)(xsw + sp*40 + cg*4) = xrv;
    }

    // ---- layer 2: gates = W21*h1_new + Whh2*h2 + b2 (bias as C operand) ----
#pragma unroll
    for (int mb = 0; mb < 4; ++mb) {
      const int p = 16*mb + cl;
      const f16x8 an0 = *(const f16x8*)(h1w + p*72 + qd*8);
      const f16x8 an1 = *(const f16x8*)(h1w + p*72 + 32 + qd*8);
      const f16x8 a20 = *(const f16x8*)(h2r + p*72 + qd*8);
      const f16x8 a21 = *(const f16x8*)(h2r + p*72 + 32 + qd*8);
      float hn[2];
#pragma unroll
      for (int rt = 0; rt < 2; ++rt) {
        f32x4 acc;
        acc = __builtin_amdgcn_mfma_f32_16x16x32_f16(w21[rt][0],  an0, b2q[rt], 0, 0, 0);
        acc = __builtin_amdgcn_mfma_f32_16x16x32_f16(w21[rt][1],  an1, acc, 0, 0, 0);
        acc = __builtin_amdgcn_mfma_f32_16x16x32_f16(whh2[rt][0], a20, acc, 0, 0, 0);
        acc = __builtin_amdgcn_mfma_f32_16x16x32_f16(whh2[rt][1], a21, acc, 0, 0, 0);
        hn[rt] = lstm_act(acc[0], acc[1], acc[2], acc[3], c2s[mb][rt]);
      }
      f16x2 hv; hv[0] = (f16)hn[0]; hv[1] = (f16)hn[1];
      *(f16x2*)(h2w + p*72 + 8*wv + 2*qd) = hv;
    }
    __syncthreads();
  }

  // ---- head epilogue: out[p] = bhead + sum_k h2[p][k] * wh[k] ----
  if (tid < 64) {
    const float* wh = (const float*)(ws + WS_WH);
    const f16* row = &h2buf[0][tid * 72];   // final h2 lives in buffer 0
    float s = *((const float*)(ws + WS_BH));
#pragma unroll
    for (int k = 0; k < 64; ++k) s += (float)row[k] * wh[k];
    out[gpix + tid] = s;
  }
}

extern "C" void kernel_launch(void* const* d_in, const int* in_sizes, int n_in,
                              void* d_out, int out_size, void* d_ws, size_t ws_size,
                              hipStream_t stream) {
  const float* x      = (const float*)d_in[0];
  const float* W_red  = (const float*)d_in[1];
  const float* b_red  = (const float*)d_in[2];
  const float* Wih1   = (const float*)d_in[3];
  const float* Whh1   = (const float*)d_in[4];
  const float* bih1   = (const float*)d_in[5];
  const float* bhh1   = (const float*)d_in[6];
  const float* Wc1    = (const float*)d_in[7];
  const float* bc1    = (const float*)d_in[8];
  const float* Wih2   = (const float*)d_in[9];
  const float* Whh2   = (const float*)d_in[10];
  const float* bih2   = (const float*)d_in[11];
  const float* bhh2   = (const float*)d_in[12];
  const float* Wc2    = (const float*)d_in[13];
  const float* bc2    = (const float*)d_in[14];
  const float* W_head = (const float*)d_in[15];
  const float* b_head = (const float*)d_in[16];

  prep_kernel<<<256, 64, 0, stream>>>(W_red, b_red, Wih1, Whh1, bih1, bhh1,
                                      Wc1, bc1, Wih2, Whh2, bih2, bhh2,
                                      Wc2, bc2, W_head, b_head,
                                      (unsigned char*)d_ws);
  convlstm_main<<<2048, 512, 0, stream>>>(x, (const unsigned char*)d_ws,
                                          (float*)d_out);
}